// Round 9
// baseline (117.054 us; speedup 1.0000x reference)
//
#include <hip/hip_runtime.h>

#define FDIM  256
#define H1D   256
#define H2D   128
#define BATCH 4096
#define NPART 32

typedef _Float16 half8 __attribute__((ext_vector_type(8)));
typedef float    f32x4 __attribute__((ext_vector_type(4)));

#define W2F_HALVES  ((size_t)FDIM * H1D * H2D)   // 8388608  (16.78 MB)
#define XH_HALVES   ((size_t)FDIM * BATCH)       // 1048576  (2 MB)
#define W1B1_HALVES ((size_t)FDIM * 8 * 4 * 16)  // 131072   (0.25 MB)

// ---------------------------------------------------------------------------
// prep_all: three independent jobs branched on blockIdx.
//  [0,2048):   W2 (f32) -> w2f f16 B-fragments, k-perm kpat(g,j)=4g+j / 16+4g+(j-4)
//  [2048,2304): x (B,F) f32 -> xh (F,B) f16 transpose via LDS tile
//  [2304,2336): W1,b1 -> w1b1 f16 packed per (f,s,g): 8 W1 halves + 8 b1 halves,
//               SAME kpat sigma as w2f (A/B K-map consistency).
// ---------------------------------------------------------------------------
__global__ __launch_bounds__(256) void prep_all(
    const float* __restrict__ x,  const float* __restrict__ W1,
    const float* __restrict__ b1, const float* __restrict__ W2,
    _Float16* __restrict__ w2f, _Float16* __restrict__ xh,
    _Float16* __restrict__ w1b1) {
    __shared__ _Float16 tile[64][66];
    const int tid = threadIdx.x;
    const int bid = blockIdx.x;
    if (bid < 2048) {
        const int f = bid >> 3, s = bid & 7;
        const int lane = tid & 63, g = lane >> 4, ln = lane & 15;
        const int w = tid >> 6;
#pragma unroll
        for (int h = 0; h < 2; ++h) {
            const int tq = w * 2 + h;
            half8 v;
#pragma unroll
            for (int j = 0; j < 8; ++j) {
                const int k = s * 32 + 4 * g + (j < 4 ? j : 12 + j);
                v[j] = (_Float16)W2[(size_t)(f * H1D + k) * H2D + tq * 16 + ln];
            }
            *(half8*)(w2f + (((size_t)(f * 8 + s) * 8 + tq) * 64 + lane) * 8) = v;
        }
    } else if (bid < 2304) {
        const int idx = bid - 2048;
        const int bt = idx >> 2, ft = idx & 3;
        const int tr = tid >> 2;          // 0..63: batch row within tile
        const int c0 = (tid & 3) * 16;    // feature col chunk
#pragma unroll
        for (int j = 0; j < 4; ++j) {
            const float4 v = *(const float4*)(
                x + (size_t)(bt * 64 + tr) * FDIM + ft * 64 + c0 + j * 4);
            tile[tr][c0 + j * 4 + 0] = (_Float16)v.x;
            tile[tr][c0 + j * 4 + 1] = (_Float16)v.y;
            tile[tr][c0 + j * 4 + 2] = (_Float16)v.z;
            tile[tr][c0 + j * 4 + 3] = (_Float16)v.w;
        }
        __syncthreads();
        const int fr = tid >> 2;          // feature row 0..63
        const int bb = (tid & 3) * 16;    // batch chunk
        half8 o0, o1;
#pragma unroll
        for (int i = 0; i < 8; ++i) o0[i] = tile[bb + i][fr];
#pragma unroll
        for (int i = 0; i < 8; ++i) o1[i] = tile[bb + 8 + i][fr];
        _Float16* dst = xh + (size_t)(ft * 64 + fr) * BATCH + bt * 64 + bb;
        *(half8*)dst = o0;
        *(half8*)(dst + 8) = o1;
    } else {
        const int idx = (bid - 2304) * 256 + tid;   // 0..8191
        const int f = idx >> 5, s = (idx >> 2) & 7, g = idx & 3;
        const float4 wlo = *(const float4*)(W1 + f * H1D + s * 32 + 4 * g);
        const float4 whi = *(const float4*)(W1 + f * H1D + s * 32 + 16 + 4 * g);
        const float4 blo = *(const float4*)(b1 + f * H1D + s * 32 + 4 * g);
        const float4 bhi = *(const float4*)(b1 + f * H1D + s * 32 + 16 + 4 * g);
        half8 wv, bv;
        wv[0] = (_Float16)wlo.x; wv[1] = (_Float16)wlo.y;
        wv[2] = (_Float16)wlo.z; wv[3] = (_Float16)wlo.w;
        wv[4] = (_Float16)whi.x; wv[5] = (_Float16)whi.y;
        wv[6] = (_Float16)whi.z; wv[7] = (_Float16)whi.w;
        bv[0] = (_Float16)blo.x; bv[1] = (_Float16)blo.y;
        bv[2] = (_Float16)blo.z; bv[3] = (_Float16)blo.w;
        bv[4] = (_Float16)bhi.x; bv[5] = (_Float16)bhi.y;
        bv[6] = (_Float16)bhi.z; bv[7] = (_Float16)bhi.w;
        _Float16* dst = w1b1 + (size_t)((f * 8 + s) * 4 + g) * 16;
        *(half8*)dst = wv;
        *(half8*)(dst + 8) = bv;
    }
}

// ---------------------------------------------------------------------------
// Main: 1024 blocks (EXACTLY 4/CU, one residency round) x 4 waves. Small
// waves, many of them: mi=2 (32 rows) x nt=4 (64 cols) x 16 features ->
// acc = 32 AGPR, ~70 VGPR, ~102 total -> 4+ waves/SIMD resident
// (launch_bounds(256,4)). VALU<->MFMA overlap comes from cross-wave
// interleave, not per-wave bursts (round 8's fat-wave attempt spilled).
// Barrier-free, LDS-free; B/W1 frags double-buffered in regs; all hot-loop
// addresses are running pointers (w2f chunks contiguous over (f,s)).
// ---------------------------------------------------------------------------
__global__ __launch_bounds__(256, 4) void coxnam_main(
    const _Float16* __restrict__ xh,  const _Float16* __restrict__ w1b1,
    const _Float16* __restrict__ w2f, const float* __restrict__ b2,
    const float* __restrict__ W3,     float* __restrict__ partial) {
    const int t    = threadIdx.x;
    const int w    = t >> 6;
    const int lane = t & 63;
    const int g = lane >> 4, ln = lane & 15;
    const int bid = blockIdx.x;                 // 0..1023
    const int xcd = bid & 7;
    const int r_  = bid >> 3;                   // 0..127
    const int fsplit = (xcd << 1) | (r_ & 1);   // 0..15  (16 features each)
    const int u   = r_ >> 1;                    // 0..63
    const int ns  = u & 1, btg = u >> 1;        // btg 0..31
    const int b0  = (btg * 4 + w) * 32;         // 32 rows per wave
    const int n0  = ns * 64, f0 = fsplit * 16;

    f32x4 acc[2][4];
    float sacc[2][4];
    _Float16 xs[2], xsn[2];
    half8 bfb[2][4], wvb[2], bvb[2];
#pragma unroll
    for (int mi = 0; mi < 2; ++mi)
#pragma unroll
        for (int r = 0; r < 4; ++r) sacc[mi][r] = 0.f;

    // running pointers (chunk stride: w2f 4096 halves, w1b1 64 halves)
    const _Float16* bp  = w2f + ((size_t)(f0 * 8) * 8 + ns * 4) * 512 + lane * 8;
    const _Float16* wb  = w1b1 + ((size_t)(f0 * 8) * 4 + g) * 16;
    const _Float16* xp  = xh + (size_t)f0 * BATCH + b0 + ln;
    const float*    b2p = b2 + f0 * H2D + n0 + ln;
    const float*    w3p = W3 + f0 * H2D + n0 + ln;

    // prologue: chunk 0 -> buffer 0; first x slice
#pragma unroll
    for (int nt = 0; nt < 4; ++nt) bfb[0][nt] = *(const half8*)(bp + (size_t)nt * 512);
    wvb[0] = *(const half8*)wb;
    bvb[0] = *(const half8*)(wb + 8);
    xs[0] = xp[0];
    xs[1] = xp[16];
    bp += 4096;
    wb += 64;

    for (int fi = 0; fi < 16; ++fi) {
        // b2 folded into accumulator init
        float b2v[4], w3v[4];
#pragma unroll
        for (int nt = 0; nt < 4; ++nt) {
            b2v[nt] = b2p[nt * 16];
            w3v[nt] = w3p[nt * 16];
        }
#pragma unroll
        for (int mi = 0; mi < 2; ++mi)
#pragma unroll
            for (int nt = 0; nt < 4; ++nt)
                acc[mi][nt] = (f32x4){b2v[nt], b2v[nt], b2v[nt], b2v[nt]};
        if (fi < 15) {
            xsn[0] = xp[BATCH];
            xsn[1] = xp[BATCH + 16];
        }
#pragma unroll
        for (int s = 0; s < 8; ++s) {
            const int cur = s & 1, nxt = cur ^ 1;   // compile-time (unrolled)
            // prefetch next chunk (runs one chunk ahead via running pointers)
            if (s < 7 || fi < 15) {
#pragma unroll
                for (int nt = 0; nt < 4; ++nt)
                    bfb[nxt][nt] = *(const half8*)(bp + (size_t)nt * 512);
                wvb[nxt] = *(const half8*)wb;
                bvb[nxt] = *(const half8*)(wb + 8);
            }
            bp += 4096;
            wb += 64;
            // A-frag recompute (packed f16) + 8 MFMA
#pragma unroll
            for (int mi = 0; mi < 2; ++mi) {
                const half8 tt = xs[mi] * wvb[cur] + bvb[cur];
                const half8 af =
                    __builtin_elementwise_max(tt, (half8)(_Float16)0.0f);
#pragma unroll
                for (int nt = 0; nt < 4; ++nt)
                    acc[mi][nt] = __builtin_amdgcn_mfma_f32_16x16x32_f16(
                        af, bfb[cur][nt], acc[mi][nt], 0, 0, 0);
            }
        }
        // ---- epilogue: relu(acc) . W3 -> sacc (b2 already inside acc) ----
#pragma unroll
        for (int mi = 0; mi < 2; ++mi)
#pragma unroll
            for (int nt = 0; nt < 4; ++nt)
#pragma unroll
                for (int r = 0; r < 4; ++r) {
                    const float v = fmaxf(acc[mi][nt][r], 0.f);
                    sacc[mi][r] = fmaf(v, w3v[nt], sacc[mi][r]);
                }
        xs[0] = xsn[0];
        xs[1] = xsn[1];
        xp  += BATCH;
        b2p += H2D;
        w3p += H2D;
    }

    // ---- reduce over the 16 n-lanes ----
#pragma unroll
    for (int mi = 0; mi < 2; ++mi)
#pragma unroll
        for (int r = 0; r < 4; ++r) {
            float v = sacc[mi][r];
            v += __shfl_xor(v, 1, 16);
            v += __shfl_xor(v, 2, 16);
            v += __shfl_xor(v, 4, 16);
            v += __shfl_xor(v, 8, 16);
            sacc[mi][r] = v;
        }
    if (ln == 0) {
        float* dst = partial + (size_t)(fsplit * 2 + ns) * BATCH + b0;
#pragma unroll
        for (int mi = 0; mi < 2; ++mi) {
            f32x4 o = {sacc[mi][0], sacc[mi][1], sacc[mi][2], sacc[mi][3]};
            *(f32x4*)(dst + mi * 16 + g * 4) = o;
        }
    }
}

// ---------------------------------------------------------------------------
// Final reduction over 32 partials + sum of b3.
// ---------------------------------------------------------------------------
__global__ __launch_bounds__(256) void reduce_out(const float* __restrict__ partial,
                                                  const float* __restrict__ b3,
                                                  float* __restrict__ out) {
    const int b = blockIdx.x * 256 + threadIdx.x;
    float v = 0.f;
#pragma unroll
    for (int p = 0; p < NPART; ++p) v += partial[(size_t)p * BATCH + b];
    float sb3 = 0.f;
#pragma unroll 4
    for (int f4 = 0; f4 < FDIM; f4 += 4) {
        const float4 t = *(const float4*)(b3 + f4);
        sb3 += t.x + t.y + t.z + t.w;
    }
    out[b] = v + sb3;
}

extern "C" void kernel_launch(void* const* d_in, const int* in_sizes, int n_in,
                              void* d_out, int out_size, void* d_ws, size_t ws_size,
                              hipStream_t stream) {
    const float* x  = (const float*)d_in[0];
    const float* W1 = (const float*)d_in[1];
    const float* b1 = (const float*)d_in[2];
    const float* W2 = (const float*)d_in[3];
    const float* b2 = (const float*)d_in[4];
    const float* W3 = (const float*)d_in[5];
    const float* b3 = (const float*)d_in[6];

    _Float16* w2f  = (_Float16*)d_ws;
    _Float16* xh   = w2f + W2F_HALVES;
    _Float16* w1b1 = xh + XH_HALVES;
    float* partial = (float*)(w1b1 + W1B1_HALVES);
    const size_t need = (W2F_HALVES + XH_HALVES + W1B1_HALVES) * sizeof(_Float16) +
                        (size_t)NPART * BATCH * sizeof(float);
    if (ws_size < need) return;  // insufficient scratch; fail visibly

    prep_all<<<2336, 256, 0, stream>>>(x, W1, b1, W2, w2f, xh, w1b1);
    coxnam_main<<<1024, 256, 0, stream>>>(xh, w1b1, w2f, b2, W3, partial);
    reduce_out<<<BATCH / 256, 256, 0, stream>>>(partial, b3, (float*)d_out);
}

// Round 10
// 86.166 us; speedup vs baseline: 1.3585x; 1.3585x over previous
//
#include <hip/hip_runtime.h>

#define FDIM  256
#define H1D   256
#define H2D   128
#define BATCH 4096
#define NPART 32

typedef _Float16 half8 __attribute__((ext_vector_type(8)));
typedef float    f32x4 __attribute__((ext_vector_type(4)));

#define W2F_HALVES  ((size_t)FDIM * H1D * H2D)   // 8388608  (16.78 MB)
#define XH_HALVES   ((size_t)FDIM * BATCH)       // 1048576  (2 MB)
#define W1B1_HALVES ((size_t)FDIM * 8 * 4 * 16)  // 131072   (0.25 MB)

// ---------------------------------------------------------------------------
// prep_all: three independent jobs branched on blockIdx.
//  [0,2048):   W2 (f32) -> w2f f16 B-fragments, k-perm kpat(g,j)=4g+j / 16+4g+(j-4)
//  [2048,2304): x (B,F) f32 -> xh (F,B) f16 transpose via LDS tile
//  [2304,2336): W1,b1 -> w1b1 f16 packed per (f,s,g): 8 W1 halves + 8 b1 halves,
//               SAME kpat sigma as w2f (A/B K-map consistency).
// ---------------------------------------------------------------------------
__global__ __launch_bounds__(256) void prep_all(
    const float* __restrict__ x,  const float* __restrict__ W1,
    const float* __restrict__ b1, const float* __restrict__ W2,
    _Float16* __restrict__ w2f, _Float16* __restrict__ xh,
    _Float16* __restrict__ w1b1) {
    __shared__ _Float16 tile[64][66];
    const int tid = threadIdx.x;
    const int bid = blockIdx.x;
    if (bid < 2048) {
        const int f = bid >> 3, s = bid & 7;
        const int lane = tid & 63, g = lane >> 4, ln = lane & 15;
        const int w = tid >> 6;
#pragma unroll
        for (int h = 0; h < 2; ++h) {
            const int tq = w * 2 + h;
            half8 v;
#pragma unroll
            for (int j = 0; j < 8; ++j) {
                const int k = s * 32 + 4 * g + (j < 4 ? j : 12 + j);
                v[j] = (_Float16)W2[(size_t)(f * H1D + k) * H2D + tq * 16 + ln];
            }
            *(half8*)(w2f + (((size_t)(f * 8 + s) * 8 + tq) * 64 + lane) * 8) = v;
        }
    } else if (bid < 2304) {
        const int idx = bid - 2048;
        const int bt = idx >> 2, ft = idx & 3;
        const int tr = tid >> 2;          // 0..63: batch row within tile
        const int c0 = (tid & 3) * 16;    // feature col chunk
#pragma unroll
        for (int j = 0; j < 4; ++j) {
            const float4 v = *(const float4*)(
                x + (size_t)(bt * 64 + tr) * FDIM + ft * 64 + c0 + j * 4);
            tile[tr][c0 + j * 4 + 0] = (_Float16)v.x;
            tile[tr][c0 + j * 4 + 1] = (_Float16)v.y;
            tile[tr][c0 + j * 4 + 2] = (_Float16)v.z;
            tile[tr][c0 + j * 4 + 3] = (_Float16)v.w;
        }
        __syncthreads();
        const int fr = tid >> 2;          // feature row 0..63
        const int bb = (tid & 3) * 16;    // batch chunk
        half8 o0, o1;
#pragma unroll
        for (int i = 0; i < 8; ++i) o0[i] = tile[bb + i][fr];
#pragma unroll
        for (int i = 0; i < 8; ++i) o1[i] = tile[bb + 8 + i][fr];
        _Float16* dst = xh + (size_t)(ft * 64 + fr) * BATCH + bt * 64 + bb;
        *(half8*)dst = o0;
        *(half8*)(dst + 8) = o1;
    } else {
        const int idx = (bid - 2304) * 256 + tid;   // 0..8191
        const int f = idx >> 5, s = (idx >> 2) & 7, g = idx & 3;
        const float4 wlo = *(const float4*)(W1 + f * H1D + s * 32 + 4 * g);
        const float4 whi = *(const float4*)(W1 + f * H1D + s * 32 + 16 + 4 * g);
        const float4 blo = *(const float4*)(b1 + f * H1D + s * 32 + 4 * g);
        const float4 bhi = *(const float4*)(b1 + f * H1D + s * 32 + 16 + 4 * g);
        half8 wv, bv;
        wv[0] = (_Float16)wlo.x; wv[1] = (_Float16)wlo.y;
        wv[2] = (_Float16)wlo.z; wv[3] = (_Float16)wlo.w;
        wv[4] = (_Float16)whi.x; wv[5] = (_Float16)whi.y;
        wv[6] = (_Float16)whi.z; wv[7] = (_Float16)whi.w;
        bv[0] = (_Float16)blo.x; bv[1] = (_Float16)blo.y;
        bv[2] = (_Float16)blo.z; bv[3] = (_Float16)blo.w;
        bv[4] = (_Float16)bhi.x; bv[5] = (_Float16)bhi.y;
        bv[6] = (_Float16)bhi.z; bv[7] = (_Float16)bhi.w;
        _Float16* dst = w1b1 + (size_t)((f * 8 + s) * 4 + g) * 16;
        *(half8*)dst = wv;
        *(half8*)(dst + 8) = bv;
    }
}

// ---------------------------------------------------------------------------
// Main: 512 blocks (EXACTLY 2/CU, one residency round) x 4 waves, 2 waves/
// SIMD ping-pong. Wave = 64 rows (mi=4) x 64 cols (nt=4) x 16 features.
// BK=64 per load round: prefetch 12 x 16B (8 B-frags + 4 w1b1) one full
// round (~620 cyc of MFMA) ahead -> L2 latency fully covered; then a
// setprio-wrapped 32-MFMA burst. acc=64 AGPR + ~132 VGPR < 256 cap: no
// spill. Barrier-free, LDS-free. Running pointers: prefetch is always
// "+8192 halves", uniform across feature boundaries.
// ---------------------------------------------------------------------------
__global__ __launch_bounds__(256, 2) void coxnam_main(
    const _Float16* __restrict__ xh,  const _Float16* __restrict__ w1b1,
    const _Float16* __restrict__ w2f, const float* __restrict__ b2,
    const float* __restrict__ W3,     float* __restrict__ partial) {
    const int t    = threadIdx.x;
    const int w    = t >> 6;
    const int lane = t & 63;
    const int g = lane >> 4, ln = lane & 15;
    const int bid = blockIdx.x;                 // 0..511
    const int xcd = bid & 7;
    const int r_  = bid >> 3;                   // 0..63
    const int fsplit = (xcd << 1) | (r_ & 1);   // 0..15 (16 features each)
    const int u   = r_ >> 1;                    // 0..31
    const int ns  = u & 1, btg = u >> 1;        // btg 0..15
    const int b0  = (btg * 4 + w) * 64;         // 64 rows per wave
    const int n0  = ns * 64, f0 = fsplit * 16;

    f32x4 acc[4][4];
    float sacc[4][4];
    half8 bfb[2][8];            // [ring][ss*4+nt]
    half8 wvb[2][2], bvb[2][2]; // [ring][ss]
    _Float16 xs[4], xsn[4];
#pragma unroll
    for (int mi = 0; mi < 4; ++mi)
#pragma unroll
        for (int r = 0; r < 4; ++r) sacc[mi][r] = 0.f;

    // running pointers (round stride: w2f 8192 halves, w1b1 128 halves)
    const _Float16* bp  = w2f + ((size_t)(f0 * 8) * 8 + ns * 4) * 512 + lane * 8;
    const _Float16* wb  = w1b1 + ((size_t)(f0 * 8) * 4 + g) * 16;
    const _Float16* xp  = xh + (size_t)f0 * BATCH + b0 + ln;
    const float*    b2p = b2 + f0 * H2D + n0 + ln;
    const float*    w3p = W3 + f0 * H2D + n0 + ln;

    // prologue: round 0 (chunks 0,1) of f0 -> ring 0; first x slice
#pragma unroll
    for (int ss = 0; ss < 2; ++ss) {
#pragma unroll
        for (int nt = 0; nt < 4; ++nt)
            bfb[0][ss * 4 + nt] = *(const half8*)(bp + ss * 4096 + nt * 512);
        wvb[0][ss] = *(const half8*)(wb + ss * 64);
        bvb[0][ss] = *(const half8*)(wb + ss * 64 + 8);
    }
#pragma unroll
    for (int mi = 0; mi < 4; ++mi) xs[mi] = xp[mi * 16];
    bp += 8192;
    wb += 128;

    for (int fi = 0; fi < 16; ++fi) {
        float b2v[4], w3v[4];
#pragma unroll
        for (int nt = 0; nt < 4; ++nt) {
            b2v[nt] = b2p[nt * 16];
            w3v[nt] = w3p[nt * 16];
        }
        // b2 folded into accumulator init
#pragma unroll
        for (int mi = 0; mi < 4; ++mi)
#pragma unroll
            for (int nt = 0; nt < 4; ++nt)
                acc[mi][nt] = (f32x4){b2v[nt], b2v[nt], b2v[nt], b2v[nt]};
        if (fi < 15) {
#pragma unroll
            for (int mi = 0; mi < 4; ++mi) xsn[mi] = xp[BATCH + mi * 16];
        }
#pragma unroll
        for (int kk = 0; kk < 4; ++kk) {              // 4 rounds x BK=64
            const int cur = kk & 1, nxt = cur ^ 1;    // compile-time
            // prefetch next round (one full 32-MFMA burst ahead)
            if (kk < 3 || fi < 15) {
#pragma unroll
                for (int ss = 0; ss < 2; ++ss) {
#pragma unroll
                    for (int nt = 0; nt < 4; ++nt)
                        bfb[nxt][ss * 4 + nt] =
                            *(const half8*)(bp + ss * 4096 + nt * 512);
                    wvb[nxt][ss] = *(const half8*)(wb + ss * 64);
                    bvb[nxt][ss] = *(const half8*)(wb + ss * 64 + 8);
                }
            }
            bp += 8192;
            wb += 128;
            // 32-MFMA burst (A-frags recomputed in regs, packed f16)
            __builtin_amdgcn_s_setprio(1);
#pragma unroll
            for (int ss = 0; ss < 2; ++ss)
#pragma unroll
                for (int mi = 0; mi < 4; ++mi) {
                    const half8 tt = xs[mi] * wvb[cur][ss] + bvb[cur][ss];
                    const half8 af =
                        __builtin_elementwise_max(tt, (half8)(_Float16)0.0f);
#pragma unroll
                    for (int nt = 0; nt < 4; ++nt)
                        acc[mi][nt] = __builtin_amdgcn_mfma_f32_16x16x32_f16(
                            af, bfb[cur][ss * 4 + nt], acc[mi][nt], 0, 0, 0);
                }
            __builtin_amdgcn_s_setprio(0);
        }
        // ---- epilogue: relu(acc) . W3 -> sacc (b2 already inside acc) ----
#pragma unroll
        for (int mi = 0; mi < 4; ++mi)
#pragma unroll
            for (int nt = 0; nt < 4; ++nt)
#pragma unroll
                for (int r = 0; r < 4; ++r) {
                    const float v = fmaxf(acc[mi][nt][r], 0.f);
                    sacc[mi][r] = fmaf(v, w3v[nt], sacc[mi][r]);
                }
#pragma unroll
        for (int mi = 0; mi < 4; ++mi) xs[mi] = xsn[mi];
        xp  += BATCH;
        b2p += H2D;
        w3p += H2D;
    }

    // ---- reduce over the 16 n-lanes ----
#pragma unroll
    for (int mi = 0; mi < 4; ++mi)
#pragma unroll
        for (int r = 0; r < 4; ++r) {
            float v = sacc[mi][r];
            v += __shfl_xor(v, 1, 16);
            v += __shfl_xor(v, 2, 16);
            v += __shfl_xor(v, 4, 16);
            v += __shfl_xor(v, 8, 16);
            sacc[mi][r] = v;
        }
    if (ln == 0) {
        float* dst = partial + (size_t)(fsplit * 2 + ns) * BATCH + b0;
#pragma unroll
        for (int mi = 0; mi < 4; ++mi) {
            f32x4 o = {sacc[mi][0], sacc[mi][1], sacc[mi][2], sacc[mi][3]};
            *(f32x4*)(dst + mi * 16 + g * 4) = o;
        }
    }
}

// ---------------------------------------------------------------------------
// Final reduction over 32 partials + sum of b3.
// ---------------------------------------------------------------------------
__global__ __launch_bounds__(256) void reduce_out(const float* __restrict__ partial,
                                                  const float* __restrict__ b3,
                                                  float* __restrict__ out) {
    const int b = blockIdx.x * 256 + threadIdx.x;
    float v = 0.f;
#pragma unroll
    for (int p = 0; p < NPART; ++p) v += partial[(size_t)p * BATCH + b];
    float sb3 = 0.f;
#pragma unroll 4
    for (int f4 = 0; f4 < FDIM; f4 += 4) {
        const float4 t = *(const float4*)(b3 + f4);
        sb3 += t.x + t.y + t.z + t.w;
    }
    out[b] = v + sb3;
}

extern "C" void kernel_launch(void* const* d_in, const int* in_sizes, int n_in,
                              void* d_out, int out_size, void* d_ws, size_t ws_size,
                              hipStream_t stream) {
    const float* x  = (const float*)d_in[0];
    const float* W1 = (const float*)d_in[1];
    const float* b1 = (const float*)d_in[2];
    const float* W2 = (const float*)d_in[3];
    const float* b2 = (const float*)d_in[4];
    const float* W3 = (const float*)d_in[5];
    const float* b3 = (const float*)d_in[6];

    _Float16* w2f  = (_Float16*)d_ws;
    _Float16* xh   = w2f + W2F_HALVES;
    _Float16* w1b1 = xh + XH_HALVES;
    float* partial = (float*)(w1b1 + W1B1_HALVES);
    const size_t need = (W2F_HALVES + XH_HALVES + W1B1_HALVES) * sizeof(_Float16) +
                        (size_t)NPART * BATCH * sizeof(float);
    if (ws_size < need) return;  // insufficient scratch; fail visibly

    prep_all<<<2336, 256, 0, stream>>>(x, W1, b1, W2, w2f, xh, w1b1);
    coxnam_main<<<512, 256, 0, stream>>>(xh, w1b1, w2f, b2, W3, partial);
    reduce_out<<<BATCH / 256, 256, 0, stream>>>(partial, b3, (float*)d_out);
}